// Round 9
// baseline (1403.784 us; speedup 1.0000x reference)
//
#include <hip/hip_runtime.h>
#include <math.h>

#define HEADS 10
#define D1 780
#define F1 78

typedef __attribute__((ext_vector_type(8))) short bf16x8;
typedef __attribute__((ext_vector_type(4))) float f32x4;

static __device__ __forceinline__ float lrelu(float x){ return x > 0.f ? x : 0.2f*x; }

static __device__ __forceinline__ unsigned short f2bf(float f){
  unsigned int u = __float_as_uint(f);
  u += 0x7fffu + ((u >> 16) & 1u);   // RNE
  return (unsigned short)(u >> 16);
}

// ---------------- CSR build ----------------
__global__ void k_count(const int* __restrict__ dst, int* __restrict__ counts, int Eraw, int N){
  int e = blockIdx.x*blockDim.x + threadIdx.x;
  if (e < Eraw + N){
    int d = (e < Eraw) ? dst[e] : (e - Eraw);
    atomicAdd(&counts[d], 1);
  }
}

__global__ void k_scan(const int* __restrict__ counts, int* __restrict__ row_ptr,
                       int* __restrict__ cursor, int N){
  __shared__ int part[1024];
  int tid = threadIdx.x;
  int chunk = (N + 1023)/1024;
  int beg = tid*chunk, end = min(beg+chunk, N);
  int s = 0;
  for (int i=beg;i<end;++i) s += counts[i];
  part[tid] = s;
  __syncthreads();
  for (int off=1; off<1024; off<<=1){
    int v = (tid >= off) ? part[tid-off] : 0;
    __syncthreads();
    part[tid] += v;
    __syncthreads();
  }
  int excl = (tid>0) ? part[tid-1] : 0;
  for (int i=beg;i<end;++i){ row_ptr[i]=excl; cursor[i]=excl; excl += counts[i]; }
  if (tid == 1023) row_ptr[N] = part[1023];
}

__global__ void k_scatter(const int* __restrict__ src, const int* __restrict__ dst,
                          int* __restrict__ cursor, int* __restrict__ col_src, int Eraw, int N){
  int e = blockIdx.x*blockDim.x + threadIdx.x;
  if (e < Eraw + N){
    int s, d;
    if (e < Eraw){ s = src[e]; d = dst[e]; } else { s = e - Eraw; d = s; }
    int pos = atomicAdd(&cursor[d], 1);
    col_src[pos] = s;
  }
}

// ---------------- one-shot prep: xb, W1T, Wsd1T, xcb, WcF ----------------
__global__ void k_prep(const float* __restrict__ x, const float* __restrict__ W1,
                       const float* __restrict__ a1s, const float* __restrict__ a1d,
                       const float* __restrict__ bg2, const float* __restrict__ bxt,
                       const float* __restrict__ Wc,
                       short* __restrict__ xb, short* __restrict__ W1T,
                       float* __restrict__ WsdT1, float* __restrict__ xcb,
                       float* __restrict__ WcF, int N){
  int id = blockIdx.x*256 + threadIdx.x;
  int r0 = N*96;
  if (id < r0){
    int row = id/96, col = id - row*96;
    xb[id] = (col < 78) ? (short)f2bf(x[row*78 + col]) : (short)0;
    return;
  }
  id -= r0;
  if (id < 780*96){
    int c = id/96, k = id - c*96;
    W1T[id] = (k < 78) ? (short)f2bf(W1[(size_t)k*780 + c]) : (short)0;
    return;
  }
  id -= 780*96;
  if (id < 20*780){
    int j = id / 780, c = id % 780;
    int h = (j < 10) ? j : j - 10;
    float v = 0.f;
    if (c / F1 == h) v = (j < 10) ? a1s[h*F1 + c%F1] : a1d[h*F1 + c%F1];
    WsdT1[id] = v;
    return;
  }
  id -= 20*780;
  if (id < 256){
    xcb[id] = (id < 128) ? bg2[id] : bxt[id-128];
    return;
  }
  id -= 256;
  if (id < 256000){
    int i = id >> 8, r = id & 255;
    WcF[id] = Wc[(size_t)(r>>3)*8000 + i*8 + (r&7)];
  }
}

// ---------------- MFMA bf16 NT GEMM, global_load_lds + both-sides swizzle + XCD chunking ----------------
// C[M,N] (+)= A[M,K] @ BT[N,K]^T. A,BT bf16 (as short), K%32==0, rows 16B-aligned.
__global__ __launch_bounds__(256) void k_mfma_nt(const short* __restrict__ A, const short* __restrict__ BT,
                        float* __restrict__ C, int M, int N, int K,
                        int lda, int ldb, int ldc, int accum, int nbx){
  __shared__ __align__(16) short As[128*32];
  __shared__ __align__(16) short Bs[128*32];
  int tid = threadIdx.x;
  int lane = tid & 63, wave = tid >> 6;
  int wr = (wave >> 1) * 64, wc = (wave & 1) * 64;

  int nwg = gridDim.x;
  int q = nwg >> 3, rr = nwg & 7;
  int xcd = blockIdx.x & 7, rank = blockIdx.x >> 3;
  int l = xcd*q + min(xcd, rr) + rank;
  int row0 = (l / nbx) * 128, col0 = (l % nbx) * 128;

  int kp = ((lane & 3) ^ ((lane >> 3) & 3)) * 8;
  int rA0 = min(row0 + wave*32 + (lane>>2), M-1);
  int rA1 = min(row0 + wave*32 + 16 + (lane>>2), M-1);
  int rB0 = min(col0 + wave*32 + (lane>>2), N-1);
  int rB1 = min(col0 + wave*32 + 16 + (lane>>2), N-1);
  const short* pa0 = A  + (size_t)rA0*lda + kp;
  const short* pa1 = A  + (size_t)rA1*lda + kp;
  const short* pb0 = BT + (size_t)rB0*ldb + kp;
  const short* pb1 = BT + (size_t)rB1*ldb + kp;
  short* la0 = As + (wave*32 + 0)*32;
  short* la1 = As + (wave*32 + 16)*32;
  short* lb0 = Bs + (wave*32 + 0)*32;
  short* lb1 = Bs + (wave*32 + 16)*32;

  int so = ((lane>>4) ^ (((lane&15)>>1)&3)) * 8;

  f32x4 acc[4][4];
  #pragma unroll
  for (int i=0;i<4;++i)
    #pragma unroll
    for (int j=0;j<4;++j) acc[i][j] = (f32x4){0.f,0.f,0.f,0.f};

  for (int k0=0; k0<K; k0+=32){
    __builtin_amdgcn_global_load_lds((const __attribute__((address_space(1))) unsigned int*)pa0,
                                     (__attribute__((address_space(3))) unsigned int*)la0, 16, 0, 0);
    __builtin_amdgcn_global_load_lds((const __attribute__((address_space(1))) unsigned int*)pa1,
                                     (__attribute__((address_space(3))) unsigned int*)la1, 16, 0, 0);
    __builtin_amdgcn_global_load_lds((const __attribute__((address_space(1))) unsigned int*)pb0,
                                     (__attribute__((address_space(3))) unsigned int*)lb0, 16, 0, 0);
    __builtin_amdgcn_global_load_lds((const __attribute__((address_space(1))) unsigned int*)pb1,
                                     (__attribute__((address_space(3))) unsigned int*)lb1, 16, 0, 0);
    pa0 += 32; pa1 += 32; pb0 += 32; pb1 += 32;
    __syncthreads();
    bf16x8 af[4], bf[4];
    #pragma unroll
    for (int rb=0;rb<4;++rb)
      af[rb] = *reinterpret_cast<const bf16x8*>(&As[(wr + rb*16 + (lane&15))*32 + so]);
    #pragma unroll
    for (int cb=0;cb<4;++cb)
      bf[cb] = *reinterpret_cast<const bf16x8*>(&Bs[(wc + cb*16 + (lane&15))*32 + so]);
    #pragma unroll
    for (int rb=0;rb<4;++rb)
      #pragma unroll
      for (int cb=0;cb<4;++cb)
        acc[rb][cb] = __builtin_amdgcn_mfma_f32_16x16x32_bf16(af[rb], bf[cb], acc[rb][cb], 0, 0, 0);
    __syncthreads();
  }
  #pragma unroll
  for (int rb=0;rb<4;++rb){
    #pragma unroll
    for (int cb=0;cb<4;++cb){
      int c = col0 + wc + cb*16 + (lane & 15);
      if (c >= N) continue;
      #pragma unroll
      for (int j=0;j<4;++j){
        int r = row0 + wr + rb*16 + (lane>>4)*4 + j;
        if (r >= M) continue;
        float v = acc[rb][cb][j];
        if (accum) v += C[(size_t)r*ldc + c];
        C[(size_t)r*ldc + c] = v;
      }
    }
  }
}

// ---------------- W2 repack: W2rT[c][h*800+k] = bf16(W2[k][h*780+c]) ----------------
__global__ void k_w2t(const float* __restrict__ W2, short* __restrict__ W2rT){
  __shared__ float s[32][33];
  int k0 = blockIdx.x*32, c0 = blockIdx.y*32, h = blockIdx.z;
  int tx = threadIdx.x, ty = threadIdx.y;
  #pragma unroll
  for (int i=0;i<32;i+=8){
    int k = k0+ty+i, c = c0+tx;
    s[ty+i][tx] = (k < 780 && c < 780) ? W2[(size_t)k*7800 + h*780 + c] : 0.f;
  }
  __syncthreads();
  #pragma unroll
  for (int i=0;i<32;i+=8){
    int c = c0+ty+i, k = k0+tx;
    if (c < 780 && k < 800)
      W2rT[(size_t)c*8000 + h*800 + k] = (short)f2bf(s[tx][ty+i]);
  }
}

// ---------------- layer-2 score projections (wave-per-output, no atomics) ----------------
__global__ __launch_bounds__(256) void k_makews2(const float* __restrict__ W2, const float* __restrict__ a2s,
                          const float* __restrict__ a2d, float* __restrict__ WsdT){
  int c = blockIdx.x;
  int wave = threadIdx.x >> 6, lane = threadIdx.x & 63;
  const float* row = W2 + (size_t)c*7800;
  for (int j = wave; j < 20; j += 4){
    int h = (j < 10) ? j : j - 10;
    const float* av = (j < 10) ? a2s : a2d;
    float s = 0.f;
    for (int e = lane; e < 780; e += 64) s += row[h*780 + e] * av[h*780 + e];
    #pragma unroll
    for (int o=32; o; o>>=1) s += __shfl_xor(s, o);
    if (lane == 0) WsdT[(size_t)j*780 + c] = s;
  }
}

// ---------------- tall-skinny projection: out[n][j] = sum_c A[n][c]*WT[j][c], j<20 ----------------
__global__ __launch_bounds__(256) void k_proj20(const float* __restrict__ A, const float* __restrict__ WT,
                        float* __restrict__ out, int N){
  int n = blockIdx.x*4 + (threadIdx.x >> 6);
  if (n >= N) return;
  int lane = threadIdx.x & 63;
  const float* row = A + (size_t)n*D1;
  float acc[20] = {};
  #pragma unroll
  for (int r=0;r<12;++r){
    int c = lane + r*64;
    float v = row[c];
    #pragma unroll
    for (int j=0;j<20;++j) acc[j] += v * WT[j*780 + c];
  }
  { int c = 768 + lane;
    if (c < D1){
      float v = row[c];
      #pragma unroll
      for (int j=0;j<20;++j) acc[j] += v * WT[j*780 + c];
    } }
  #pragma unroll
  for (int j=0;j<20;++j){
    #pragma unroll
    for (int off=32; off; off>>=1) acc[j] += __shfl_xor(acc[j], off);
  }
  #pragma unroll
  for (int j=0;j<20;++j) if (lane == j) out[(size_t)n*20 + j] = acc[j];
}

// ---------------- GAT layer 1 aggregation (predicated unrolled gather) ----------------
__global__ __launch_bounds__(256) void k_agg1(const float* __restrict__ h1, const float* __restrict__ hsd,
                       const int* __restrict__ row_ptr, const int* __restrict__ col_src,
                       const float* __restrict__ b1, float* __restrict__ g1o){
  __shared__ float m_l[HEADS], s_l[HEADS];
  __shared__ float al[16][HEADS];
  __shared__ int src_l[16];
  int n = blockIdx.x, tid = threadIdx.x;
  int beg = row_ptr[n], end = row_ptr[n+1];
  if (tid < HEADS){
    float hdv = hsd[(size_t)n*20 + 10 + tid];
    float m = -1e30f;
    for (int j=beg;j<end;++j) m = fmaxf(m, lrelu(hsd[(size_t)col_src[j]*20 + tid] + hdv));
    float s = 0.f;
    for (int j=beg;j<end;++j) s += expf(lrelu(hsd[(size_t)col_src[j]*20 + tid] + hdv) - m);
    m_l[tid]=m; s_l[tid]=s;
  }
  __syncthreads();
  float4 a4 = {0.f,0.f,0.f,0.f};
  int c0 = tid*4;
  int h0 = c0/F1, h1i = (c0+1)/F1, h2 = (c0+2)/F1, h3 = (c0+3)/F1;
  for (int j0=beg; j0<end; j0+=16){
    int cn = min(16, end-j0);
    for (int p=tid; p<16*HEADS; p+=256){
      int j = p/HEADS, h = p - j*HEADS;
      int valid = (j < cn);
      int sidx = col_src[j0 + (valid ? j : 0)];
      if (h==0) src_l[j] = sidx;
      float a = 0.f;
      if (valid){
        float sc = lrelu(hsd[(size_t)sidx*20 + h] + hsd[(size_t)n*20 + 10 + h]);
        a = expf(sc - m_l[h]) / s_l[h];
      }
      al[j][h] = a;
    }
    __syncthreads();
    if (tid < 195){
      #pragma unroll
      for (int j=0;j<16;++j){
        if (j >= cn) break;           // cn is block-uniform -> uniform branch
        const float4* hr4 = reinterpret_cast<const float4*>(h1 + (size_t)src_l[j]*D1);
        float4 v = hr4[tid];
        a4.x += al[j][h0]*v.x;
        a4.y += al[j][h1i]*v.y;
        a4.z += al[j][h2]*v.z;
        a4.w += al[j][h3]*v.w;
      }
    }
    __syncthreads();
  }
  if (tid < 195){
    float4 o;
    float v0 = a4.x + b1[c0];   o.x = v0 > 0.f ? v0 : expm1f(v0);
    float v1 = a4.y + b1[c0+1]; o.y = v1 > 0.f ? v1 : expm1f(v1);
    float v2 = a4.z + b1[c0+2]; o.z = v2 > 0.f ? v2 : expm1f(v2);
    float v3 = a4.w + b1[c0+3]; o.w = v3 > 0.f ? v3 : expm1f(v3);
    *reinterpret_cast<float4*>(g1o + (size_t)n*D1 + c0) = o;
  }
}

// ---------------- layer-2 aggregation (predicated unrolled) -> aggB bf16 [N][G*800] ----------------
template<int G>
__global__ __launch_bounds__(256) void k_aggG(const float* __restrict__ g1, const float* __restrict__ hsd,
                       const int* __restrict__ row_ptr, const int* __restrict__ col_src,
                       short* __restrict__ aggB, int h0){
  __shared__ float m_l[G], s_l[G];
  __shared__ float al[16][G];
  __shared__ int src_l[16];
  int n = blockIdx.x, tid = threadIdx.x;
  int beg = row_ptr[n], end = row_ptr[n+1];
  if (tid < G){
    int h = h0 + tid;
    float hdv = hsd[(size_t)n*20 + 10 + h];
    float m = -1e30f;
    for (int j=beg;j<end;++j) m = fmaxf(m, lrelu(hsd[(size_t)col_src[j]*20 + h] + hdv));
    float s = 0.f;
    for (int j=beg;j<end;++j) s += expf(lrelu(hsd[(size_t)col_src[j]*20 + h] + hdv) - m);
    m_l[tid]=m; s_l[tid]=s;
  }
  __syncthreads();
  float acc[4][G] = {};
  for (int j0=beg; j0<end; j0+=16){
    int cn = min(16, end-j0);
    for (int p=tid; p<16*G; p+=256){
      int j = p/G, g = p - j*G;
      int valid = (j < cn);
      int sidx = col_src[j0 + (valid ? j : 0)];
      if (g==0) src_l[j] = sidx;
      float a = 0.f;
      if (valid){
        int h = h0 + g;
        float hdv = hsd[(size_t)n*20 + 10 + h];
        a = 0.1f * expf(lrelu(hsd[(size_t)sidx*20 + h] + hdv) - m_l[g]) / s_l[g];
      }
      al[j][g] = a;
    }
    __syncthreads();
    if (tid < 195){
      #pragma unroll
      for (int j=0;j<16;++j){
        if (j >= cn) break;           // uniform branch
        const float4* gr4 = reinterpret_cast<const float4*>(g1 + (size_t)src_l[j]*D1);
        float4 v = gr4[tid];
        #pragma unroll
        for (int g=0;g<G;++g){
          float a = al[j][g];
          acc[0][g] += a*v.x; acc[1][g] += a*v.y;
          acc[2][g] += a*v.z; acc[3][g] += a*v.w;
        }
      }
    }
    __syncthreads();
  }
  short* og = aggB + (size_t)n*G*800;
  if (tid < 195){
    int c0 = tid*4;
    #pragma unroll
    for (int g=0;g<G;++g){
      ushort4 o;
      o.x = f2bf(acc[0][g]); o.y = f2bf(acc[1][g]);
      o.z = f2bf(acc[2][g]); o.w = f2bf(acc[3][g]);
      *reinterpret_cast<ushort4*>(og + g*800 + c0) = o;
    }
  }
  for (int p=tid; p<G*20; p+=256){ int g=p/20, c2=780+p%20; og[g*800 + c2] = 0; }
}

// ---------------- pooling (col-split) ----------------
__device__ __forceinline__ int lowb(const int* a, int n, int v){
  int lo=0, hi=n;
  while (lo<hi){ int mid=(lo+hi)>>1; if (a[mid]<v) lo=mid+1; else hi=mid; }
  return lo;
}

__global__ void k_pool(const float* __restrict__ out2, const float* __restrict__ b2,
                       const int* __restrict__ batch, int N, float* __restrict__ gfeat){
  int b = blockIdx.x;
  int c = blockIdx.y*256 + threadIdx.x;
  if (c >= D1) return;
  int lo = lowb(batch, N, b), hi = lowb(batch, N, b+1);
  float bb = b2[c];
  float mx = -INFINITY, sm = 0.f;
  for (int n2=lo;n2<hi;++n2){
    float v = fmaxf(out2[(size_t)n2*D1 + c] + bb, 0.f);
    mx = fmaxf(mx, v);
    sm += v;
  }
  int cnt = hi-lo;
  gfeat[(size_t)b*1560 + c] = mx;
  gfeat[(size_t)b*1560 + 780 + c] = sm / fmaxf((float)cnt, 1.f);
}

// ---------------- protein conv: rank-26 factorization ----------------
__global__ __launch_bounds__(256) void k_prot(const int* __restrict__ target, const float* __restrict__ WcF,
                       const float* __restrict__ emb, const float* __restrict__ bc,
                       float* __restrict__ convc){
  __shared__ float Q[256*27];
  __shared__ float emb_l[26*128];
  __shared__ int tg_l[1000];
  int b = blockIdx.x, tid = threadIdx.x;
  for (int i=tid;i<26*128;i+=256) emb_l[i]=emb[i];
  for (int i=tid;i<1000;i+=256) tg_l[i]=target[b*1000+i];
  for (int i=tid;i<256*27;i+=256) Q[i]=0.f;
  __syncthreads();
  float* q = Q + tid*27;
  for (int i=0;i<1000;++i){
    float w = WcF[i*256 + tid];
    q[tg_l[i]] += w;
  }
  __syncthreads();
  for (int p=tid; p<32*121; p+=256){
    int o = p/121, t = p%121;
    float acc = bc[o];
    const float* qb = Q + (o*8)*27;
    for (int v=0; v<26; ++v){
      const float* ev = emb_l + v*128 + t;
      #pragma unroll
      for (int k=0;k<8;++k) acc += qb[k*27 + v] * ev[k];
    }
    convc[(size_t)b*3872 + p] = acc;
  }
}

// ---------------- split-K skinny GEMM (M<=64) with fused A-side bias/act ----------------
__global__ __launch_bounds__(256) void k_skinny(const float* __restrict__ A, const float* __restrict__ B,
                        float* __restrict__ C, int M, int N, int K, int ldb, int ldc, int kc,
                        const float* __restrict__ biasA, int actA){
  int col0 = blockIdx.x*64;
  int k0 = blockIdx.y*kc, k1 = min(K, k0+kc);
  int tx = threadIdx.x & 63, ty = threadIdx.x >> 6;
  int col = col0 + tx;
  if (col >= N) return;
  float acc[16] = {};
  for (int k=k0; k<k1; ++k){
    float b = B[(size_t)k*ldb + col];
    float bA = biasA ? biasA[k] : 0.f;
    bool doRelu = (actA == 1) || (actA == 2 && k < 128);
    const float* Ak = A + (size_t)(ty*16)*K + k;
    #pragma unroll
    for (int i=0;i<16;++i){
      float a = Ak[(size_t)i*K] + bA;
      if (doRelu) a = fmaxf(a, 0.f);
      acc[i] += a * b;
    }
  }
  #pragma unroll
  for (int i=0;i<16;++i){
    int r = ty*16 + i;
    if (r < M) atomicAdd(&C[(size_t)r*ldc + col], acc[i]);
  }
}

// ---------------- final Wo dot (f2 bias+relu fused) ----------------
__global__ void k_wo(const float* __restrict__ f2, const float* __restrict__ bf2,
                     const float* __restrict__ Wo, const float* __restrict__ bo,
                     float* __restrict__ out, int M){
  __shared__ float red[256];
  int tid = threadIdx.x;
  int r = tid & 63, kg = tid >> 6;
  float p = 0.f;
  for (int k = kg*128; k < kg*128 + 128; ++k)
    p += fmaxf(f2[(size_t)r*512 + k] + bf2[k], 0.f) * Wo[k];
  red[tid] = p;
  __syncthreads();
  if (tid < 64 && tid < M) out[tid] = red[tid] + red[tid+64] + red[tid+128] + red[tid+192] + bo[0];
}

// ---------------- launch ----------------
extern "C" void kernel_launch(void* const* d_in, const int* in_sizes, int n_in,
                              void* d_out, int out_size, void* d_ws, size_t ws_size,
                              hipStream_t stream){
  const float* x   = (const float*)d_in[0];
  const int*   ei    = (const int*)d_in[1];
  const int*   batch = (const int*)d_in[2];
  const int*   target= (const int*)d_in[3];
  const float* W1  = (const float*)d_in[4];
  const float* a1s = (const float*)d_in[5];
  const float* a1d = (const float*)d_in[6];
  const float* b1  = (const float*)d_in[7];
  const float* W2  = (const float*)d_in[8];
  const float* a2s = (const float*)d_in[9];
  const float* a2d = (const float*)d_in[10];
  const float* b2  = (const float*)d_in[11];
  const float* Wg1 = (const float*)d_in[12];
  const float* bg1 = (const float*)d_in[13];
  const float* Wg2 = (const float*)d_in[14];
  const float* bg2 = (const float*)d_in[15];
  const float* emb = (const float*)d_in[16];
  const float* Wc  = (const float*)d_in[17];
  const float* bc  = (const float*)d_in[18];
  const float* Wxt = (const float*)d_in[19];
  const float* bxt = (const float*)d_in[20];
  const float* Wf1 = (const float*)d_in[21];
  const float* bf1 = (const float*)d_in[22];
  const float* Wf2 = (const float*)d_in[23];
  const float* bf2 = (const float*)d_in[24];
  const float* Wo  = (const float*)d_in[25];
  const float* bo  = (const float*)d_in[26];

  int N = in_sizes[0] / 78;
  int Eraw = in_sizes[1] / 2;
  int Bb = in_sizes[3] / 1000;
  int Etot = Eraw + N;

  char* wsp = (char*)d_ws;
  size_t off = 0;
  auto alloc = [&](size_t bytes)->void*{ void* p = wsp + off; off += (bytes + 255) & ~(size_t)255; return p; };
  float* buf1   = (float*)alloc((size_t)N*D1*4);   // h1
  float* buf2   = (float*)alloc((size_t)N*D1*4);   // g1
  float* buf3   = (float*)alloc((size_t)N*D1*4);   // out2
  float* hsd1   = (float*)alloc((size_t)N*20*4);
  float* hsd2   = (float*)alloc((size_t)N*20*4);
  float* WsdT1  = (float*)alloc((size_t)20*D1*4);
  float* WsdT2  = (float*)alloc((size_t)20*D1*4);
  int*   row_ptr= (int*)alloc((size_t)(N+1)*4);
  int*   cursor = (int*)alloc((size_t)N*4);
  int*   col_src= (int*)alloc((size_t)Etot*4);
  float* WcF    = (float*)alloc((size_t)1000*256*4);
  float* convc  = (float*)alloc((size_t)Bb*3872*4);
  float* gfeat  = (float*)alloc((size_t)Bb*1560*4);
  short* xb     = (short*)alloc((size_t)N*96*2);
  short* W1T    = (short*)alloc((size_t)780*96*2);
  float* xcb    = (float*)alloc((size_t)256*4);
  // ---- contiguous zero region: counts, fcg1, xc, f1, f2 ----
  size_t zbeg = off;
  int*   counts = (int*)alloc((size_t)N*4);
  float* fcg1   = (float*)alloc((size_t)Bb*1500*4);
  float* xc     = (float*)alloc((size_t)Bb*256*4);
  float* f1     = (float*)alloc((size_t)Bb*1024*4);
  float* f2     = (float*)alloc((size_t)Bb*512*4);
  size_t zlen = off - zbeg;
  short* W2rT   = (short*)alloc((size_t)D1*8000*2);  // [c][h*800+k] bf16
  int G = 10;
  { size_t avail = (ws_size > off + (1u<<20)) ? ws_size - off - (1u<<20) : 0;
    if      (avail >= (size_t)N*10*800*2) G = 10;
    else if (avail >= (size_t)N*5*800*2)  G = 5;
    else if (avail >= (size_t)N*2*800*2)  G = 2;
    else                                   G = 1; }
  short* aggB = (short*)alloc((size_t)N*G*800*2);
  (void)n_in; (void)out_size;

  // ---- zero all atomic-target buffers in one memset ----
  hipMemsetAsync(wsp + zbeg, 0, zlen, stream);

  // ---- one-shot prep (xb, W1T, Wsd1T, xcb, WcF) ----
  { int tot = N*96 + 780*96 + 20*780 + 256 + 256000;
    k_prep<<<(tot+255)/256,256,0,stream>>>(x, W1, a1s, a1d, bg2, bxt, Wc,
                                           xb, W1T, WsdT1, xcb, WcF, N); }

  // ---- CSR by dst (self-loops appended) ----
  int thr=256, blk=(Etot+thr-1)/thr;
  k_count<<<blk,thr,0,stream>>>(ei+Eraw, counts, Eraw, N);
  k_scan<<<1,1024,0,stream>>>(counts, row_ptr, cursor, N);
  k_scatter<<<blk,thr,0,stream>>>(ei, ei+Eraw, cursor, col_src, Eraw, N);

  // ---- protein branch: rank-26 factorization ----
  k_prot<<<Bb,256,0,stream>>>(target, WcF, emb, bc, convc);
  { dim3 g((128+63)/64, (3872+127)/128);
    k_skinny<<<g,256,0,stream>>>(convc, Wxt, xc+128, Bb, 128, 3872, 128, 256, 128, nullptr, 0); }

  // ---- GAT layer 1 (MFMA W1 projection) ----
  int nbx = (D1+127)/128, nby = (N+127)/128;
  k_mfma_nt<<<nbx*nby,256,0,stream>>>(xb, W1T, buf1, N, D1, 96, 96, 96, D1, 0, nbx);
  k_proj20<<<(N+3)/4,256,0,stream>>>(buf1, WsdT1, hsd1, N);
  k_agg1<<<N,256,0,stream>>>(buf1, hsd1, row_ptr, col_src, b1, buf2);

  // ---- GAT layer 2 ----
  k_makews2<<<D1,256,0,stream>>>(W2, a2s, a2d, WsdT2);
  k_proj20<<<(N+3)/4,256,0,stream>>>(buf2, WsdT2, hsd2, N);
  { dim3 g(25, 25, 10); dim3 b(32, 8);
    k_w2t<<<g,b,0,stream>>>(W2, W2rT); }

  float* out2 = buf3;
  // split heavy GEMM into two M-halves (diagnostic: surfaces the true #2 dispatch)
  int nby1 = nby/2, M1 = nby1*128;
  for (int h0=0; h0<HEADS; h0+=G){
    switch (G){
      case 10: k_aggG<10><<<N,256,0,stream>>>(buf2, hsd2, row_ptr, col_src, aggB, h0); break;
      case 5:  k_aggG<5> <<<N,256,0,stream>>>(buf2, hsd2, row_ptr, col_src, aggB, h0); break;
      case 2:  k_aggG<2> <<<N,256,0,stream>>>(buf2, hsd2, row_ptr, col_src, aggB, h0); break;
      default: k_aggG<1> <<<N,256,0,stream>>>(buf2, hsd2, row_ptr, col_src, aggB, h0); break;
    }
    k_mfma_nt<<<nbx*nby1,256,0,stream>>>(aggB, W2rT + h0*800, out2, M1, D1,
                                         G*800, G*800, 8000, D1, h0?1:0, nbx);
    k_mfma_nt<<<nbx*(nby-nby1),256,0,stream>>>(aggB + (size_t)M1*G*800, W2rT + h0*800,
                                               out2 + (size_t)M1*D1, N - M1, D1,
                                               G*800, G*800, 8000, D1, h0?1:0, nbx);
  }

  // ---- pooling (bias+relu fused, col-split) ----
  { dim3 gp(Bb, 4);
    k_pool<<<gp,256,0,stream>>>(out2, b2, batch, N, gfeat); }

  // ---- graph FCs (split-K skinny, A-side bias/act fused) ----
  { dim3 g((1500+63)/64, (1560+127)/128);
    k_skinny<<<g,256,0,stream>>>(gfeat, Wg1, fcg1, Bb, 1500, 1560, 1500, 1500, 128, nullptr, 0); }
  { dim3 g((128+63)/64, (1500+127)/128);
    k_skinny<<<g,256,0,stream>>>(fcg1, Wg2, xc, Bb, 128, 1500, 128, 256, 128, bg1, 1); }

  // ---- fusion MLP ----
  { dim3 g((1024+63)/64, (256+127)/128);
    k_skinny<<<g,256,0,stream>>>(xc, Wf1, f1, Bb, 1024, 256, 1024, 1024, 128, xcb, 2); }
  { dim3 g((512+63)/64, (1024+127)/128);
    k_skinny<<<g,256,0,stream>>>(f1, Wf2, f2, Bb, 512, 1024, 512, 512, 128, bf1, 1); }
  k_wo<<<1,256,0,stream>>>(f2, bf2, Wo, bo, (float*)d_out, Bb);
}

// Round 10
// 943.655 us; speedup vs baseline: 1.4876x; 1.4876x over previous
//
#include <hip/hip_runtime.h>
#include <math.h>

#define HEADS 10
#define D1 780
#define F1 78

typedef __attribute__((ext_vector_type(8))) short bf16x8;
typedef __attribute__((ext_vector_type(4))) float f32x4;

static __device__ __forceinline__ float lrelu(float x){ return x > 0.f ? x : 0.2f*x; }

static __device__ __forceinline__ unsigned short f2bf(float f){
  unsigned int u = __float_as_uint(f);
  u += 0x7fffu + ((u >> 16) & 1u);   // RNE
  return (unsigned short)(u >> 16);
}

// ---------------- CSR build ----------------
__global__ void k_count(const int* __restrict__ dst, int* __restrict__ counts, int Eraw, int N){
  int e = blockIdx.x*blockDim.x + threadIdx.x;
  if (e < Eraw + N){
    int d = (e < Eraw) ? dst[e] : (e - Eraw);
    atomicAdd(&counts[d], 1);
  }
}

__global__ void k_scan(const int* __restrict__ counts, int* __restrict__ row_ptr,
                       int* __restrict__ cursor, int N){
  __shared__ int part[1024];
  int tid = threadIdx.x;
  int chunk = (N + 1023)/1024;
  int beg = tid*chunk, end = min(beg+chunk, N);
  int s = 0;
  for (int i=beg;i<end;++i) s += counts[i];
  part[tid] = s;
  __syncthreads();
  for (int off=1; off<1024; off<<=1){
    int v = (tid >= off) ? part[tid-off] : 0;
    __syncthreads();
    part[tid] += v;
    __syncthreads();
  }
  int excl = (tid>0) ? part[tid-1] : 0;
  for (int i=beg;i<end;++i){ row_ptr[i]=excl; cursor[i]=excl; excl += counts[i]; }
  if (tid == 1023) row_ptr[N] = part[1023];
}

__global__ void k_scatter(const int* __restrict__ src, const int* __restrict__ dst,
                          int* __restrict__ cursor, int* __restrict__ col_src, int Eraw, int N){
  int e = blockIdx.x*blockDim.x + threadIdx.x;
  if (e < Eraw + N){
    int s, d;
    if (e < Eraw){ s = src[e]; d = dst[e]; } else { s = e - Eraw; d = s; }
    int pos = atomicAdd(&cursor[d], 1);
    col_src[pos] = s;
  }
}

// ---------------- one-shot prep: xb, W1T, Wsd1T, xcb, WcF ----------------
__global__ void k_prep(const float* __restrict__ x, const float* __restrict__ W1,
                       const float* __restrict__ a1s, const float* __restrict__ a1d,
                       const float* __restrict__ bg2, const float* __restrict__ bxt,
                       const float* __restrict__ Wc,
                       short* __restrict__ xb, short* __restrict__ W1T,
                       float* __restrict__ WsdT1, float* __restrict__ xcb,
                       float* __restrict__ WcF, int N){
  int id = blockIdx.x*256 + threadIdx.x;
  int r0 = N*96;
  if (id < r0){
    int row = id/96, col = id - row*96;
    xb[id] = (col < 78) ? (short)f2bf(x[row*78 + col]) : (short)0;
    return;
  }
  id -= r0;
  if (id < 780*96){
    int c = id/96, k = id - c*96;
    W1T[id] = (k < 78) ? (short)f2bf(W1[(size_t)k*780 + c]) : (short)0;
    return;
  }
  id -= 780*96;
  if (id < 20*780){
    int j = id / 780, c = id % 780;
    int h = (j < 10) ? j : j - 10;
    float v = 0.f;
    if (c / F1 == h) v = (j < 10) ? a1s[h*F1 + c%F1] : a1d[h*F1 + c%F1];
    WsdT1[id] = v;
    return;
  }
  id -= 20*780;
  if (id < 256){
    xcb[id] = (id < 128) ? bg2[id] : bxt[id-128];
    return;
  }
  id -= 256;
  if (id < 256000){
    int i = id >> 8, r = id & 255;
    WcF[id] = Wc[(size_t)(r>>3)*8000 + i*8 + (r&7)];
  }
}

// ---------------- MFMA bf16 NT GEMM, global_load_lds + both-sides swizzle + XCD chunking ----------------
__global__ __launch_bounds__(256) void k_mfma_nt(const short* __restrict__ A, const short* __restrict__ BT,
                        float* __restrict__ C, int M, int N, int K,
                        int lda, int ldb, int ldc, int accum, int nbx){
  __shared__ __align__(16) short As[128*32];
  __shared__ __align__(16) short Bs[128*32];
  int tid = threadIdx.x;
  int lane = tid & 63, wave = tid >> 6;
  int wr = (wave >> 1) * 64, wc = (wave & 1) * 64;

  int nwg = gridDim.x;
  int q = nwg >> 3, rr = nwg & 7;
  int xcd = blockIdx.x & 7, rank = blockIdx.x >> 3;
  int l = xcd*q + min(xcd, rr) + rank;
  int row0 = (l / nbx) * 128, col0 = (l % nbx) * 128;

  int kp = ((lane & 3) ^ ((lane >> 3) & 3)) * 8;
  int rA0 = min(row0 + wave*32 + (lane>>2), M-1);
  int rA1 = min(row0 + wave*32 + 16 + (lane>>2), M-1);
  int rB0 = min(col0 + wave*32 + (lane>>2), N-1);
  int rB1 = min(col0 + wave*32 + 16 + (lane>>2), N-1);
  const short* pa0 = A  + (size_t)rA0*lda + kp;
  const short* pa1 = A  + (size_t)rA1*lda + kp;
  const short* pb0 = BT + (size_t)rB0*ldb + kp;
  const short* pb1 = BT + (size_t)rB1*ldb + kp;
  short* la0 = As + (wave*32 + 0)*32;
  short* la1 = As + (wave*32 + 16)*32;
  short* lb0 = Bs + (wave*32 + 0)*32;
  short* lb1 = Bs + (wave*32 + 16)*32;

  int so = ((lane>>4) ^ (((lane&15)>>1)&3)) * 8;

  f32x4 acc[4][4];
  #pragma unroll
  for (int i=0;i<4;++i)
    #pragma unroll
    for (int j=0;j<4;++j) acc[i][j] = (f32x4){0.f,0.f,0.f,0.f};

  for (int k0=0; k0<K; k0+=32){
    __builtin_amdgcn_global_load_lds((const __attribute__((address_space(1))) unsigned int*)pa0,
                                     (__attribute__((address_space(3))) unsigned int*)la0, 16, 0, 0);
    __builtin_amdgcn_global_load_lds((const __attribute__((address_space(1))) unsigned int*)pa1,
                                     (__attribute__((address_space(3))) unsigned int*)la1, 16, 0, 0);
    __builtin_amdgcn_global_load_lds((const __attribute__((address_space(1))) unsigned int*)pb0,
                                     (__attribute__((address_space(3))) unsigned int*)lb0, 16, 0, 0);
    __builtin_amdgcn_global_load_lds((const __attribute__((address_space(1))) unsigned int*)pb1,
                                     (__attribute__((address_space(3))) unsigned int*)lb1, 16, 0, 0);
    pa0 += 32; pa1 += 32; pb0 += 32; pb1 += 32;
    __syncthreads();
    bf16x8 af[4], bf[4];
    #pragma unroll
    for (int rb=0;rb<4;++rb)
      af[rb] = *reinterpret_cast<const bf16x8*>(&As[(wr + rb*16 + (lane&15))*32 + so]);
    #pragma unroll
    for (int cb=0;cb<4;++cb)
      bf[cb] = *reinterpret_cast<const bf16x8*>(&Bs[(wc + cb*16 + (lane&15))*32 + so]);
    #pragma unroll
    for (int rb=0;rb<4;++rb)
      #pragma unroll
      for (int cb=0;cb<4;++cb)
        acc[rb][cb] = __builtin_amdgcn_mfma_f32_16x16x32_bf16(af[rb], bf[cb], acc[rb][cb], 0, 0, 0);
    __syncthreads();
  }
  #pragma unroll
  for (int rb=0;rb<4;++rb){
    #pragma unroll
    for (int cb=0;cb<4;++cb){
      int c = col0 + wc + cb*16 + (lane & 15);
      if (c >= N) continue;
      #pragma unroll
      for (int j=0;j<4;++j){
        int r = row0 + wr + rb*16 + (lane>>4)*4 + j;
        if (r >= M) continue;
        float v = acc[rb][cb][j];
        if (accum) v += C[(size_t)r*ldc + c];
        C[(size_t)r*ldc + c] = v;
      }
    }
  }
}

// ---------------- W2 repack: W2rT[c][h*800+k] = bf16(W2[k][h*780+c]) ----------------
__global__ void k_w2t(const float* __restrict__ W2, short* __restrict__ W2rT){
  __shared__ float s[32][33];
  int k0 = blockIdx.x*32, c0 = blockIdx.y*32, h = blockIdx.z;
  int tx = threadIdx.x, ty = threadIdx.y;
  #pragma unroll
  for (int i=0;i<32;i+=8){
    int k = k0+ty+i, c = c0+tx;
    s[ty+i][tx] = (k < 780 && c < 780) ? W2[(size_t)k*7800 + h*780 + c] : 0.f;
  }
  __syncthreads();
  #pragma unroll
  for (int i=0;i<32;i+=8){
    int c = c0+ty+i, k = k0+tx;
    if (c < 780 && k < 800)
      W2rT[(size_t)c*8000 + h*800 + k] = (short)f2bf(s[tx][ty+i]);
  }
}

// ---------------- layer-2 score projections (wave-per-j, grid (780,5)) ----------------
__global__ __launch_bounds__(256) void k_makews2(const float* __restrict__ W2, const float* __restrict__ a2s,
                          const float* __restrict__ a2d, float* __restrict__ WsdT){
  int c = blockIdx.x;
  int j = blockIdx.y*4 + (threadIdx.x >> 6);
  int lane = threadIdx.x & 63;
  if (j >= 20) return;
  int h = (j < 10) ? j : j - 10;
  const float* av = (j < 10) ? a2s : a2d;
  const float* row = W2 + (size_t)c*7800 + h*780;
  const float* ah = av + h*780;
  float s = 0.f;
  for (int e = lane; e < 780; e += 64) s += row[e] * ah[e];
  #pragma unroll
  for (int o=32; o; o>>=1) s += __shfl_xor(s, o);
  if (lane == 0) WsdT[(size_t)j*780 + c] = s;
}

// ---------------- tall-skinny projection: out[n][j] = sum_c A[n][c]*WT[j][c], j<20 ----------------
__global__ __launch_bounds__(256) void k_proj20(const float* __restrict__ A, const float* __restrict__ WT,
                        float* __restrict__ out, int N){
  int n = blockIdx.x*4 + (threadIdx.x >> 6);
  if (n >= N) return;
  int lane = threadIdx.x & 63;
  const float* row = A + (size_t)n*D1;
  float acc[20] = {};
  #pragma unroll
  for (int r=0;r<12;++r){
    int c = lane + r*64;
    float v = row[c];
    #pragma unroll
    for (int j=0;j<20;++j) acc[j] += v * WT[j*780 + c];
  }
  { int c = 768 + lane;
    if (c < D1){
      float v = row[c];
      #pragma unroll
      for (int j=0;j<20;++j) acc[j] += v * WT[j*780 + c];
    } }
  #pragma unroll
  for (int j=0;j<20;++j){
    #pragma unroll
    for (int off=32; off; off>>=1) acc[j] += __shfl_xor(acc[j], off);
  }
  #pragma unroll
  for (int j=0;j<20;++j) if (lane == j) out[(size_t)n*20 + j] = acc[j];
}

// ---------------- GAT layer 1 aggregation (predicated unrolled gather) ----------------
__global__ __launch_bounds__(256) void k_agg1(const float* __restrict__ h1, const float* __restrict__ hsd,
                       const int* __restrict__ row_ptr, const int* __restrict__ col_src,
                       const float* __restrict__ b1, float* __restrict__ g1o){
  __shared__ float m_l[HEADS], s_l[HEADS];
  __shared__ float al[16][HEADS];
  __shared__ int src_l[16];
  int n = blockIdx.x, tid = threadIdx.x;
  int beg = row_ptr[n], end = row_ptr[n+1];
  if (tid < HEADS){
    float hdv = hsd[(size_t)n*20 + 10 + tid];
    float m = -1e30f;
    for (int j=beg;j<end;++j) m = fmaxf(m, lrelu(hsd[(size_t)col_src[j]*20 + tid] + hdv));
    float s = 0.f;
    for (int j=beg;j<end;++j) s += expf(lrelu(hsd[(size_t)col_src[j]*20 + tid] + hdv) - m);
    m_l[tid]=m; s_l[tid]=s;
  }
  __syncthreads();
  float4 a4 = {0.f,0.f,0.f,0.f};
  int c0 = tid*4;
  int h0 = c0/F1, h1i = (c0+1)/F1, h2 = (c0+2)/F1, h3 = (c0+3)/F1;
  for (int j0=beg; j0<end; j0+=16){
    int cn = min(16, end-j0);
    for (int p=tid; p<16*HEADS; p+=256){
      int j = p/HEADS, h = p - j*HEADS;
      int valid = (j < cn);
      int sidx = col_src[j0 + (valid ? j : 0)];
      if (h==0) src_l[j] = sidx;
      float a = 0.f;
      if (valid){
        float sc = lrelu(hsd[(size_t)sidx*20 + h] + hsd[(size_t)n*20 + 10 + h]);
        a = expf(sc - m_l[h]) / s_l[h];
      }
      al[j][h] = a;
    }
    __syncthreads();
    if (tid < 195){
      #pragma unroll
      for (int j=0;j<16;++j){
        if (j >= cn) break;           // cn is block-uniform -> uniform branch
        const float4* hr4 = reinterpret_cast<const float4*>(h1 + (size_t)src_l[j]*D1);
        float4 v = hr4[tid];
        a4.x += al[j][h0]*v.x;
        a4.y += al[j][h1i]*v.y;
        a4.z += al[j][h2]*v.z;
        a4.w += al[j][h3]*v.w;
      }
    }
    __syncthreads();
  }
  if (tid < 195){
    float4 o;
    float v0 = a4.x + b1[c0];   o.x = v0 > 0.f ? v0 : expm1f(v0);
    float v1 = a4.y + b1[c0+1]; o.y = v1 > 0.f ? v1 : expm1f(v1);
    float v2 = a4.z + b1[c0+2]; o.z = v2 > 0.f ? v2 : expm1f(v2);
    float v3 = a4.w + b1[c0+3]; o.w = v3 > 0.f ? v3 : expm1f(v3);
    *reinterpret_cast<float4*>(g1o + (size_t)n*D1 + c0) = o;
  }
}

// ---------------- layer-2 aggregation (predicated unrolled) -> aggB bf16 [N][G*800] ----------------
template<int G>
__global__ __launch_bounds__(256) void k_aggG(const float* __restrict__ g1, const float* __restrict__ hsd,
                       const int* __restrict__ row_ptr, const int* __restrict__ col_src,
                       short* __restrict__ aggB, int h0){
  __shared__ float m_l[G], s_l[G];
  __shared__ float al[16][G];
  __shared__ int src_l[16];
  int n = blockIdx.x, tid = threadIdx.x;
  int beg = row_ptr[n], end = row_ptr[n+1];
  if (tid < G){
    int h = h0 + tid;
    float hdv = hsd[(size_t)n*20 + 10 + h];
    float m = -1e30f;
    for (int j=beg;j<end;++j) m = fmaxf(m, lrelu(hsd[(size_t)col_src[j]*20 + h] + hdv));
    float s = 0.f;
    for (int j=beg;j<end;++j) s += expf(lrelu(hsd[(size_t)col_src[j]*20 + h] + hdv) - m);
    m_l[tid]=m; s_l[tid]=s;
  }
  __syncthreads();
  float acc[4][G] = {};
  for (int j0=beg; j0<end; j0+=16){
    int cn = min(16, end-j0);
    for (int p=tid; p<16*G; p+=256){
      int j = p/G, g = p - j*G;
      int valid = (j < cn);
      int sidx = col_src[j0 + (valid ? j : 0)];
      if (g==0) src_l[j] = sidx;
      float a = 0.f;
      if (valid){
        int h = h0 + g;
        float hdv = hsd[(size_t)n*20 + 10 + h];
        a = 0.1f * expf(lrelu(hsd[(size_t)sidx*20 + h] + hdv) - m_l[g]) / s_l[g];
      }
      al[j][g] = a;
    }
    __syncthreads();
    if (tid < 195){
      #pragma unroll
      for (int j=0;j<16;++j){
        if (j >= cn) break;           // uniform branch
        const float4* gr4 = reinterpret_cast<const float4*>(g1 + (size_t)src_l[j]*D1);
        float4 v = gr4[tid];
        #pragma unroll
        for (int g=0;g<G;++g){
          float a = al[j][g];
          acc[0][g] += a*v.x; acc[1][g] += a*v.y;
          acc[2][g] += a*v.z; acc[3][g] += a*v.w;
        }
      }
    }
    __syncthreads();
  }
  short* og = aggB + (size_t)n*G*800;
  if (tid < 195){
    int c0 = tid*4;
    #pragma unroll
    for (int g=0;g<G;++g){
      ushort4 o;
      o.x = f2bf(acc[0][g]); o.y = f2bf(acc[1][g]);
      o.z = f2bf(acc[2][g]); o.w = f2bf(acc[3][g]);
      *reinterpret_cast<ushort4*>(og + g*800 + c0) = o;
    }
  }
  for (int p=tid; p<G*20; p+=256){ int g=p/20, c2=780+p%20; og[g*800 + c2] = 0; }
}

// ---------------- pooling (col-split) ----------------
__device__ __forceinline__ int lowb(const int* a, int n, int v){
  int lo=0, hi=n;
  while (lo<hi){ int mid=(lo+hi)>>1; if (a[mid]<v) lo=mid+1; else hi=mid; }
  return lo;
}

__global__ void k_pool(const float* __restrict__ out2, const float* __restrict__ b2,
                       const int* __restrict__ batch, int N, float* __restrict__ gfeat){
  int b = blockIdx.x;
  int c = blockIdx.y*256 + threadIdx.x;
  if (c >= D1) return;
  int lo = lowb(batch, N, b), hi = lowb(batch, N, b+1);
  float bb = b2[c];
  float mx = -INFINITY, sm = 0.f;
  for (int n2=lo;n2<hi;++n2){
    float v = fmaxf(out2[(size_t)n2*D1 + c] + bb, 0.f);
    mx = fmaxf(mx, v);
    sm += v;
  }
  int cnt = hi-lo;
  gfeat[(size_t)b*1560 + c] = mx;
  gfeat[(size_t)b*1560 + 780 + c] = sm / fmaxf((float)cnt, 1.f);
}

// ---------------- protein conv: rank-26, 8-way i-split partials ----------------
// Qp[((b*8+seg)*26 + v)*256 + r] = sum_{i in seg} WcF[i][r]*[tg[i]==v]
__global__ __launch_bounds__(256) void k_protQ(const int* __restrict__ target, const float* __restrict__ WcF,
                        float* __restrict__ Qp){
  __shared__ float Q[256*27];
  __shared__ int tg_l[125];
  int b = blockIdx.x, seg = blockIdx.y, tid = threadIdx.x;
  int i0 = seg*125;
  if (tid < 125) tg_l[tid] = target[b*1000 + i0 + tid];
  for (int i=tid;i<256*27;i+=256) Q[i]=0.f;
  __syncthreads();
  float* q = Q + tid*27;
  for (int i=0;i<125;++i){
    float w = WcF[(size_t)(i0+i)*256 + tid];
    q[tg_l[i]] += w;
  }
  __syncthreads();
  float* op = Qp + ((size_t)(b*8+seg)*26)*256;
  for (int v=0; v<26; ++v) op[v*256 + tid] = q[v];
}

// convc[b][o*121+t] = bc[o] + sum_v sum_k (sum_seg Qp[b][seg][v][o*8+k]) * emb[v][t+k]
__global__ __launch_bounds__(128) void k_protC(const float* __restrict__ Qp, const float* __restrict__ emb,
                        const float* __restrict__ bc, float* __restrict__ convc){
  __shared__ float emb_l[26*128];
  __shared__ float Qs[208];
  int b = blockIdx.x, o = blockIdx.y, tid = threadIdx.x;
  for (int i=tid;i<26*128;i+=128) emb_l[i]=emb[i];
  for (int idx=tid; idx<208; idx+=128){
    int k = idx/26, v = idx%26;
    float s = 0.f;
    #pragma unroll
    for (int seg=0;seg<8;++seg)
      s += Qp[((size_t)(b*8+seg)*26 + v)*256 + (o*8+k)];
    Qs[idx] = s;
  }
  __syncthreads();
  if (tid < 121){
    float acc = bc[o];
    for (int v=0; v<26; ++v){
      const float* ev = emb_l + v*128 + tid;
      #pragma unroll
      for (int k=0;k<8;++k) acc += Qs[k*26 + v] * ev[k];
    }
    convc[(size_t)b*3872 + o*121 + tid] = acc;
  }
}

// ---------------- split-K skinny GEMM (M<=64) with fused A-side bias/act ----------------
__global__ __launch_bounds__(256) void k_skinny(const float* __restrict__ A, const float* __restrict__ B,
                        float* __restrict__ C, int M, int N, int K, int ldb, int ldc, int kc,
                        const float* __restrict__ biasA, int actA){
  int col0 = blockIdx.x*64;
  int k0 = blockIdx.y*kc, k1 = min(K, k0+kc);
  int tx = threadIdx.x & 63, ty = threadIdx.x >> 6;
  int col = col0 + tx;
  if (col >= N) return;
  float acc[16] = {};
  for (int k=k0; k<k1; ++k){
    float b = B[(size_t)k*ldb + col];
    float bA = biasA ? biasA[k] : 0.f;
    bool doRelu = (actA == 1) || (actA == 2 && k < 128);
    const float* Ak = A + (size_t)(ty*16)*K + k;
    #pragma unroll
    for (int i=0;i<16;++i){
      float a = Ak[(size_t)i*K] + bA;
      if (doRelu) a = fmaxf(a, 0.f);
      acc[i] += a * b;
    }
  }
  #pragma unroll
  for (int i=0;i<16;++i){
    int r = ty*16 + i;
    if (r < M) atomicAdd(&C[(size_t)r*ldc + col], acc[i]);
  }
}

// ---------------- final Wo dot (f2 bias+relu fused) ----------------
__global__ void k_wo(const float* __restrict__ f2, const float* __restrict__ bf2,
                     const float* __restrict__ Wo, const float* __restrict__ bo,
                     float* __restrict__ out, int M){
  __shared__ float red[256];
  int tid = threadIdx.x;
  int r = tid & 63, kg = tid >> 6;
  float p = 0.f;
  for (int k = kg*128; k < kg*128 + 128; ++k)
    p += fmaxf(f2[(size_t)r*512 + k] + bf2[k], 0.f) * Wo[k];
  red[tid] = p;
  __syncthreads();
  if (tid < 64 && tid < M) out[tid] = red[tid] + red[tid+64] + red[tid+128] + red[tid+192] + bo[0];
}

// ---------------- launch ----------------
extern "C" void kernel_launch(void* const* d_in, const int* in_sizes, int n_in,
                              void* d_out, int out_size, void* d_ws, size_t ws_size,
                              hipStream_t stream){
  const float* x   = (const float*)d_in[0];
  const int*   ei    = (const int*)d_in[1];
  const int*   batch = (const int*)d_in[2];
  const int*   target= (const int*)d_in[3];
  const float* W1  = (const float*)d_in[4];
  const float* a1s = (const float*)d_in[5];
  const float* a1d = (const float*)d_in[6];
  const float* b1  = (const float*)d_in[7];
  const float* W2  = (const float*)d_in[8];
  const float* a2s = (const float*)d_in[9];
  const float* a2d = (const float*)d_in[10];
  const float* b2  = (const float*)d_in[11];
  const float* Wg1 = (const float*)d_in[12];
  const float* bg1 = (const float*)d_in[13];
  const float* Wg2 = (const float*)d_in[14];
  const float* bg2 = (const float*)d_in[15];
  const float* emb = (const float*)d_in[16];
  const float* Wc  = (const float*)d_in[17];
  const float* bc  = (const float*)d_in[18];
  const float* Wxt = (const float*)d_in[19];
  const float* bxt = (const float*)d_in[20];
  const float* Wf1 = (const float*)d_in[21];
  const float* bf1 = (const float*)d_in[22];
  const float* Wf2 = (const float*)d_in[23];
  const float* bf2 = (const float*)d_in[24];
  const float* Wo  = (const float*)d_in[25];
  const float* bo  = (const float*)d_in[26];

  int N = in_sizes[0] / 78;
  int Eraw = in_sizes[1] / 2;
  int Bb = in_sizes[3] / 1000;
  int Etot = Eraw + N;

  char* wsp = (char*)d_ws;
  size_t off = 0;
  auto alloc = [&](size_t bytes)->void*{ void* p = wsp + off; off += (bytes + 255) & ~(size_t)255; return p; };
  float* buf1   = (float*)alloc((size_t)N*D1*4);   // h1
  float* buf2   = (float*)alloc((size_t)N*D1*4);   // g1
  float* buf3   = (float*)alloc((size_t)N*D1*4);   // out2
  float* hsd1   = (float*)alloc((size_t)N*20*4);
  float* hsd2   = (float*)alloc((size_t)N*20*4);
  float* WsdT1  = (float*)alloc((size_t)20*D1*4);
  float* WsdT2  = (float*)alloc((size_t)20*D1*4);
  int*   row_ptr= (int*)alloc((size_t)(N+1)*4);
  int*   cursor = (int*)alloc((size_t)N*4);
  int*   col_src= (int*)alloc((size_t)Etot*4);
  float* WcF    = (float*)alloc((size_t)1000*256*4);
  float* Qp     = (float*)alloc((size_t)Bb*8*26*256*4);
  float* convc  = (float*)alloc((size_t)Bb*3872*4);
  float* gfeat  = (float*)alloc((size_t)Bb*1560*4);
  short* xb     = (short*)alloc((size_t)N*96*2);
  short* W1T    = (short*)alloc((size_t)780*96*2);
  float* xcb    = (float*)alloc((size_t)256*4);
  // ---- contiguous zero region: counts, fcg1, xc, f1, f2 ----
  size_t zbeg = off;
  int*   counts = (int*)alloc((size_t)N*4);
  float* fcg1   = (float*)alloc((size_t)Bb*1500*4);
  float* xc     = (float*)alloc((size_t)Bb*256*4);
  float* f1     = (float*)alloc((size_t)Bb*1024*4);
  float* f2     = (float*)alloc((size_t)Bb*512*4);
  size_t zlen = off - zbeg;
  short* W2rT   = (short*)alloc((size_t)D1*8000*2);  // [c][h*800+k] bf16
  int G = 10;
  { size_t avail = (ws_size > off + (1u<<20)) ? ws_size - off - (1u<<20) : 0;
    if      (avail >= (size_t)N*10*800*2) G = 10;
    else if (avail >= (size_t)N*5*800*2)  G = 5;
    else if (avail >= (size_t)N*2*800*2)  G = 2;
    else                                   G = 1; }
  short* aggB = (short*)alloc((size_t)N*G*800*2);
  (void)n_in; (void)out_size;

  // ---- zero all atomic-target buffers in one memset ----
  hipMemsetAsync(wsp + zbeg, 0, zlen, stream);

  // ---- one-shot prep (xb, W1T, Wsd1T, xcb, WcF) ----
  { int tot = N*96 + 780*96 + 20*780 + 256 + 256000;
    k_prep<<<(tot+255)/256,256,0,stream>>>(x, W1, a1s, a1d, bg2, bxt, Wc,
                                           xb, W1T, WsdT1, xcb, WcF, N); }

  // ---- CSR by dst (self-loops appended) ----
  int thr=256, blk=(Etot+thr-1)/thr;
  k_count<<<blk,thr,0,stream>>>(ei+Eraw, counts, Eraw, N);
  k_scan<<<1,1024,0,stream>>>(counts, row_ptr, cursor, N);
  k_scatter<<<blk,thr,0,stream>>>(ei, ei+Eraw, cursor, col_src, Eraw, N);

  // ---- protein branch: rank-26, parallel Q build + combine ----
  { dim3 gq(Bb, 8);
    k_protQ<<<gq,256,0,stream>>>(target, WcF, Qp); }
  { dim3 gc(Bb, 32);
    k_protC<<<gc,128,0,stream>>>(Qp, emb, bc, convc); }
  { dim3 g((128+63)/64, (3872+31)/32);
    k_skinny<<<g,256,0,stream>>>(convc, Wxt, xc+128, Bb, 128, 3872, 128, 256, 32, nullptr, 0); }

  // ---- GAT layer 1 (MFMA W1 projection) ----
  int nbx = (D1+127)/128, nby = (N+127)/128;
  k_mfma_nt<<<nbx*nby,256,0,stream>>>(xb, W1T, buf1, N, D1, 96, 96, 96, D1, 0, nbx);
  k_proj20<<<(N+3)/4,256,0,stream>>>(buf1, WsdT1, hsd1, N);
  k_agg1<<<N,256,0,stream>>>(buf1, hsd1, row_ptr, col_src, b1, buf2);

  // ---- GAT layer 2 ----
  { dim3 gm(D1, 5);
    k_makews2<<<gm,256,0,stream>>>(W2, a2s, a2d, WsdT2); }
  k_proj20<<<(N+3)/4,256,0,stream>>>(buf2, WsdT2, hsd2, N);
  { dim3 g(25, 25, 10); dim3 b(32, 8);
    k_w2t<<<g,b,0,stream>>>(W2, W2rT); }

  float* out2 = buf3;
  for (int h0=0; h0<HEADS; h0+=G){
    switch (G){
      case 10: k_aggG<10><<<N,256,0,stream>>>(buf2, hsd2, row_ptr, col_src, aggB, h0); break;
      case 5:  k_aggG<5> <<<N,256,0,stream>>>(buf2, hsd2, row_ptr, col_src, aggB, h0); break;
      case 2:  k_aggG<2> <<<N,256,0,stream>>>(buf2, hsd2, row_ptr, col_src, aggB, h0); break;
      default: k_aggG<1> <<<N,256,0,stream>>>(buf2, hsd2, row_ptr, col_src, aggB, h0); break;
    }
    k_mfma_nt<<<nbx*nby,256,0,stream>>>(aggB, W2rT + h0*800, out2, N, D1, G*800, G*800, 8000, D1, h0?1:0, nbx);
  }

  // ---- pooling (bias+relu fused, col-split) ----
  { dim3 gp(Bb, 4);
    k_pool<<<gp,256,0,stream>>>(out2, b2, batch, N, gfeat); }

  // ---- graph FCs (split-K skinny, A-side bias/act fused) ----
  { dim3 g((1500+63)/64, (1560+127)/128);
    k_skinny<<<g,256,0,stream>>>(gfeat, Wg1, fcg1, Bb, 1500, 1560, 1500, 1500, 128, nullptr, 0); }
  { dim3 g((128+63)/64, (1500+31)/32);
    k_skinny<<<g,256,0,stream>>>(fcg1, Wg2, xc, Bb, 128, 1500, 128, 256, 32, bg1, 1); }

  // ---- fusion MLP ----
  { dim3 g((1024+63)/64, (256+31)/32);
    k_skinny<<<g,256,0,stream>>>(xc, Wf1, f1, Bb, 1024, 256, 1024, 1024, 32, xcb, 2); }
  { dim3 g((512+63)/64, (1024+31)/32);
    k_skinny<<<g,256,0,stream>>>(f1, Wf2, f2, Bb, 512, 1024, 512, 512, 32, bf1, 1); }
  k_wo<<<1,256,0,stream>>>(f2, bf2, Wo, bo, (float*)d_out, Bb);
}